// Round 1
// baseline (24249.321 us; speedup 1.0000x reference)
//
#include <hip/hip_runtime.h>
#include <math.h>

#define N 8192
#define D 256
#define BM 64
#define BN 64
#define BK 32

// ---------------- weight clip + renormalize ----------------
__global__ void prep_wc(const float* __restrict__ w, float* __restrict__ wc) {
    int t = threadIdx.x;  // 256 threads
    float v = fminf(fmaxf(w[t], 0.0f), 2.0f);
    float s = v;
#pragma unroll
    for (int m = 1; m < 64; m <<= 1) s += __shfl_xor(s, m);
    __shared__ float sm[4];
    if ((t & 63) == 0) sm[t >> 6] = s;
    __syncthreads();
    float mean = (sm[0] + sm[1] + sm[2] + sm[3]) * (1.0f / 256.0f);
    wc[t] = v / mean;
}

// ---------------- row-normalize a = wc*x1 and b = x2 ----------------
__global__ void prep_normalize(const float* __restrict__ x1, const float* __restrict__ x2,
                               const float* __restrict__ wc,
                               float* __restrict__ an, float* __restrict__ bn) {
    int row = blockIdx.x;  // 0..16383
    int t = threadIdx.x;   // 0..255
    int r;
    float v;
    float* dst;
    if (row < N) { r = row;     v = x1[r * D + t] * wc[t]; dst = an; }
    else         { r = row - N; v = x2[r * D + t];         dst = bn; }
    float ss = v * v;
#pragma unroll
    for (int m = 1; m < 64; m <<= 1) ss += __shfl_xor(ss, m);
    __shared__ float sm[4];
    if ((t & 63) == 0) sm[t >> 6] = ss;
    __syncthreads();
    float denom = sqrtf(sm[0] + sm[1] + sm[2] + sm[3]) + 1e-12f;
    dst[r * D + t] = v / denom;
}

// ---------------- fused cost + softmin (flash-style online LSE) ----------------
// out_i = -eps * ( log_w + LSE_j( (pot_j - 1 + a_i.b_j) / eps ) )
// tasks: 0: fxx(Cxx) [avg]  1: gyy(Cyy) [avg]  2: f(Cxy)  3: g(Cxy^T)
__global__ __launch_bounds__(256) void softmin_all(
    const float* __restrict__ an, const float* __restrict__ bn,
    const float* __restrict__ f_in, const float* __restrict__ g_in,
    const float* __restrict__ fxx_in, const float* __restrict__ gyy_in,
    float* __restrict__ f_out, float* __restrict__ g_out,
    float* __restrict__ fxx_out, float* __restrict__ gyy_out,
    float eps, float log_w, int do_avg) {
    int task = blockIdx.x >> 7;   // 128 row-blocks per task
    int rb = blockIdx.x & 127;
    const float* A; const float* B; const float* pot; float* out; int avg;
    switch (task) {
        case 0:  A = an; B = an; pot = fxx_in; out = fxx_out; avg = do_avg; break;
        case 1:  A = bn; B = bn; pot = gyy_in; out = gyy_out; avg = do_avg; break;
        case 2:  A = an; B = bn; pot = g_in;   out = f_out;   avg = 0;      break;
        default: A = bn; B = an; pot = f_in;   out = g_out;   avg = 0;      break;
    }

    __shared__ float As[BK][BM + 4];  // transposed: As[k][row]; stride 68 keeps 16B alignment
    __shared__ float Bs[BK][BN + 4];

    const int t = threadIdx.x;
    const int tx = t & 15;   // column group (4 cols each)
    const int ty = t >> 4;   // row group   (4 rows each)
    const int i0 = rb * BM;
    const float inv_eps = 1.0f / eps;

    float mrun[4], srun[4];
#pragma unroll
    for (int ii = 0; ii < 4; ++ii) { mrun[ii] = -INFINITY; srun[ii] = 0.0f; }

    for (int jt = 0; jt < N / BN; ++jt) {
        const int j0 = jt * BN;
        float acc[4][4];
#pragma unroll
        for (int ii = 0; ii < 4; ++ii)
#pragma unroll
            for (int jj = 0; jj < 4; ++jj) acc[ii][jj] = 0.0f;

        for (int k0 = 0; k0 < D; k0 += BK) {
            __syncthreads();
            // stage A/B chunks (64 rows x 32 k), transposed into LDS
#pragma unroll
            for (int p = 0; p < 2; ++p) {
                int idx = t + p * 256;        // 0..511
                int row = idx >> 3;           // 8 float4 per row of 32 k
                int c4  = idx & 7;
                float4 av = *(const float4*)&A[(size_t)(i0 + row) * D + k0 + c4 * 4];
                float4 bv = *(const float4*)&B[(size_t)(j0 + row) * D + k0 + c4 * 4];
                As[c4 * 4 + 0][row] = av.x; As[c4 * 4 + 1][row] = av.y;
                As[c4 * 4 + 2][row] = av.z; As[c4 * 4 + 3][row] = av.w;
                Bs[c4 * 4 + 0][row] = bv.x; Bs[c4 * 4 + 1][row] = bv.y;
                Bs[c4 * 4 + 2][row] = bv.z; Bs[c4 * 4 + 3][row] = bv.w;
            }
            __syncthreads();
#pragma unroll
            for (int kk = 0; kk < BK; ++kk) {
                float4 a4 = *(const float4*)&As[kk][ty * 4];
                float4 b4 = *(const float4*)&Bs[kk][tx * 4];
                float a[4] = {a4.x, a4.y, a4.z, a4.w};
                float b[4] = {b4.x, b4.y, b4.z, b4.w};
#pragma unroll
                for (int ii = 0; ii < 4; ++ii)
#pragma unroll
                    for (int jj = 0; jj < 4; ++jj)
                        acc[ii][jj] = fmaf(a[ii], b[jj], acc[ii][jj]);
            }
        }

        // online LSE update for this 64-col tile
        float pj[4];
#pragma unroll
        for (int jj = 0; jj < 4; ++jj) pj[jj] = pot[j0 + tx * 4 + jj];
#pragma unroll
        for (int ii = 0; ii < 4; ++ii) {
            float l[4];
#pragma unroll
            for (int jj = 0; jj < 4; ++jj)
                l[jj] = (pj[jj] - 1.0f + acc[ii][jj]) * inv_eps;
            float tm = fmaxf(fmaxf(l[0], l[1]), fmaxf(l[2], l[3]));
#pragma unroll
            for (int m = 1; m < 16; m <<= 1) tm = fmaxf(tm, __shfl_xor(tm, m));
            float mnew = fmaxf(mrun[ii], tm);
            float p = __expf(l[0] - mnew) + __expf(l[1] - mnew) +
                      __expf(l[2] - mnew) + __expf(l[3] - mnew);
#pragma unroll
            for (int m = 1; m < 16; m <<= 1) p += __shfl_xor(p, m);
            srun[ii] = srun[ii] * __expf(mrun[ii] - mnew) + p;
            mrun[ii] = mnew;
        }
    }

    if (tx == 0) {
#pragma unroll
        for (int ii = 0; ii < 4; ++ii) {
            int i = i0 + ty * 4 + ii;
            float v = -eps * (log_w + mrun[ii] + __logf(srun[ii]));
            if (avg) v = 0.5f * (pot[i] + v);  // row-pot == pot array for tasks 0/1
            out[i] = v;
        }
    }
}

// ---------------- final scalar reduce ----------------
__global__ void final_reduce(const float* __restrict__ f, const float* __restrict__ g,
                             const float* __restrict__ fxx, const float* __restrict__ gyy,
                             float* __restrict__ out) {
    int t = threadIdx.x;
    float s = 0.0f;
    for (int i = t; i < N; i += 256) s += (f[i] - fxx[i]) + (g[i] - gyy[i]);
#pragma unroll
    for (int m = 1; m < 64; m <<= 1) s += __shfl_xor(s, m);
    __shared__ float sm[4];
    if ((t & 63) == 0) sm[t >> 6] = s;
    __syncthreads();
    if (t == 0) out[0] = (sm[0] + sm[1] + sm[2] + sm[3]) * (1.0f / (float)N);
}

extern "C" void kernel_launch(void* const* d_in, const int* in_sizes, int n_in,
                              void* d_out, int out_size, void* d_ws, size_t ws_size,
                              hipStream_t stream) {
    const float* x1 = (const float*)d_in[0];
    const float* x2 = (const float*)d_in[1];
    const float* w  = (const float*)d_in[2];
    float* out = (float*)d_out;

    float* ws = (float*)d_ws;
    float* wc = ws;                    // 256
    float* an = wc + 256;              // 8192*256
    float* bn = an + (size_t)N * D;    // 8192*256
    float* P0 = bn + (size_t)N * D;    // 4*8192: f,g,fxx,gyy
    float* P1 = P0 + 4 * N;

    hipMemsetAsync(P0, 0, 4 * N * sizeof(float), stream);
    prep_wc<<<1, 256, 0, stream>>>(w, wc);
    prep_normalize<<<2 * N, 256, 0, stream>>>(x1, x2, wc, an, bn);

    // eps schedule: 4,1,0.25,0.0625,0.015625,0.00390625, then 0.0025 x4
    const float eps_list[10] = {4.0f, 1.0f, 0.25f, 0.0625f, 0.015625f,
                                0.00390625f, 0.0025f, 0.0025f, 0.0025f, 0.0025f};
    const float log_w = -logf((float)N);
    float* bufs[2] = {P0, P1};
    for (int it = 0; it < 10; ++it) {
        float* pin = bufs[it & 1];
        float* po  = bufs[(it + 1) & 1];
        softmin_all<<<512, 256, 0, stream>>>(
            an, bn, pin + 0, pin + N, pin + 2 * N, pin + 3 * N,
            po + 0, po + N, po + 2 * N, po + 3 * N,
            eps_list[it], log_w, 1);
    }
    // after 10 iters (even), final potentials are in P0; extrapolate (no averaging) into P1
    softmin_all<<<512, 256, 0, stream>>>(
        an, bn, P0 + 0, P0 + N, P0 + 2 * N, P0 + 3 * N,
        P1 + 0, P1 + N, P1 + 2 * N, P1 + 3 * N,
        0.0025f, log_w, 0);
    final_reduce<<<1, 256, 0, stream>>>(P1 + 0, P1 + N, P1 + 2 * N, P1 + 3 * N, out);
}

// Round 2
// 2443.563 us; speedup vs baseline: 9.9238x; 9.9238x over previous
//
#include <hip/hip_runtime.h>
#include <math.h>

#define N 8192
#define D 256
#define KP 272          // j-panel width in bf16 elements: 256 data + 16 ext (pot hi/lo at 256,257)
#define LN2 0.6931471805599453f

typedef short short8 __attribute__((ext_vector_type(8)));
typedef float f32x16 __attribute__((ext_vector_type(16)));
typedef unsigned short ushort;

__device__ __forceinline__ float fexp2(float x) { return __builtin_amdgcn_exp2f(x); }
__device__ __forceinline__ float flog2(float x) { return __builtin_amdgcn_logf(x); }

__device__ __forceinline__ ushort bf16r(float x) {  // RNE f32 -> bf16
    unsigned int u = __float_as_uint(x);
    return (ushort)((u + 0x7FFF + ((u >> 16) & 1)) >> 16);
}
__device__ __forceinline__ float bf16f(ushort h) {
    return __uint_as_float(((unsigned int)h) << 16);
}

// ---------------- weight clip + renormalize ----------------
__global__ void prep_wc(const float* __restrict__ w, float* __restrict__ wc) {
    int t = threadIdx.x;  // 256
    float v = fminf(fmaxf(w[t], 0.0f), 2.0f);
    float s = v;
#pragma unroll
    for (int m = 1; m < 64; m <<= 1) s += __shfl_xor(s, m);
    __shared__ float sm[4];
    if ((t & 63) == 0) sm[t >> 6] = s;
    __syncthreads();
    float mean = (sm[0] + sm[1] + sm[2] + sm[3]) * (1.0f / 256.0f);
    wc[t] = v / mean;
}

// ---------------- normalize rows, emit bf16 i-panels + j-panels ----------------
// x1 rows -> an_i, pan0 (fxx pot), pan3 (f pot);  x2 rows -> bn_i, pan1 (gyy), pan2 (g)
__global__ void prep_normalize(const float* __restrict__ x1, const float* __restrict__ x2,
                               const float* __restrict__ wc,
                               ushort* __restrict__ an_i, ushort* __restrict__ bn_i,
                               ushort* __restrict__ pan0, ushort* __restrict__ pan1,
                               ushort* __restrict__ pan2, ushort* __restrict__ pan3) {
    int row = blockIdx.x;  // 0..16383
    int t = threadIdx.x;   // 0..255
    int r; float v;
    ushort *ip, *pa, *pb;
    if (row < N) { r = row;     v = x1[(size_t)r * D + t] * wc[t]; ip = an_i; pa = pan0; pb = pan3; }
    else         { r = row - N; v = x2[(size_t)r * D + t];         ip = bn_i; pa = pan1; pb = pan2; }
    float ss = v * v;
#pragma unroll
    for (int m = 1; m < 64; m <<= 1) ss += __shfl_xor(ss, m);
    __shared__ float sm[4];
    if ((t & 63) == 0) sm[t >> 6] = ss;
    __syncthreads();
    float denom = sqrtf(sm[0] + sm[1] + sm[2] + sm[3]) + 1e-12f;
    ushort b = bf16r(v / denom);
    ip[(size_t)r * D + t] = b;
    pa[(size_t)r * KP + t] = b;
    pb[(size_t)r * KP + t] = b;
    if (t < 16) {  // ext cols: pot=0 -> pterm=-1 -> hi=0xBF80, lo=0; cols 258..271 zero
        ushort e = (t == 0) ? (ushort)0xBF80 : (ushort)0;
        pa[(size_t)r * KP + 256 + t] = e;
        pb[(size_t)r * KP + 256 + t] = e;
    }
}

// ---------------- fused cost + softmin via MFMA (flash-style, no LDS) ----------------
// tasks: 0: fxx (j=an, pot=fxx)  1: gyy (j=bn, pot=gyy)  2: f (j=bn, pot=g)  3: g (j=an, pot=f)
// Swapped operands: A_op = j-side frags (streamed from L2), B_op = i-side frags (registers).
// D layout: col = lane&31 = i  -> one output row per lane per acc tile; regs/halves = j's.
__global__ __launch_bounds__(256, 2) void softmin_mfma(
    const ushort* __restrict__ an_i, const ushort* __restrict__ bn_i,
    const ushort* __restrict__ pan0, const ushort* __restrict__ pan1,
    const ushort* __restrict__ pan2, const ushort* __restrict__ pan3,
    float2* __restrict__ parts, float k1) {  // k1 = log2(e)/eps
    int bx = blockIdx.x;
    int task = bx >> 7;           // 4 tasks x 32 rb x 4 splits
    int rb = (bx >> 2) & 31;
    int split = bx & 3;
    const ushort* jp; const ushort* ip;
    switch (task) {
        case 0:  jp = pan0; ip = an_i; break;
        case 1:  jp = pan1; ip = bn_i; break;
        case 2:  jp = pan2; ip = an_i; break;
        default: jp = pan3; ip = bn_i; break;
    }
    int t = threadIdx.x;
    int wave = t >> 6, lane = t & 63;
    int l31 = lane & 31, lh = lane >> 5;
    int i0 = rb * 256 + wave * 64;  // this wave: rows [i0, i0+64)

    // B_op (i-side) fragments, K=256 (16 chunks) + pot chunk, for two 32-row sets
    short8 bi0[17], bi1[17];
    const ushort* ib = ip + (size_t)(i0 + l31) * D + lh * 8;
#pragma unroll
    for (int c = 0; c < 16; ++c) {
        bi0[c] = *(const short8*)(ib + c * 16);
        bi1[c] = *(const short8*)(ib + (size_t)32 * D + c * 16);
    }
    short8 pz = {};  // pot chunk B_op: a_ext[i][256]=a_ext[i][257]=1.0
    if (lh == 0) { pz[0] = (short)0x3F80; pz[1] = (short)0x3F80; }
    bi0[16] = pz; bi1[16] = pz;

    float m0 = -INFINITY, s0 = 0.0f, m1 = -INFINITY, s1 = 0.0f;
    const ushort* jbase = jp + (size_t)(split * 2048 + l31) * KP + lh * 8;

    for (int js = 0; js < 64; ++js) {  // 32 j's per step, 2048 per split
        const ushort* ar = jbase + (size_t)js * 32 * KP;
        f32x16 acc0 = {}; f32x16 acc1 = {};
#pragma unroll
        for (int c = 0; c < 17; ++c) {
            short8 af = *(const short8*)(ar + c * 16);
            acc0 = __builtin_amdgcn_mfma_f32_32x32x16_bf16(af, bi0[c], acc0, 0, 0, 0);
            acc1 = __builtin_amdgcn_mfma_f32_32x32x16_bf16(af, bi1[c], acc1, 0, 0, 0);
        }
        // acc = cos_sim + (pot_j - 1); online LSE in base-2, per lane (one row per set)
        {
            float tv[16];
#pragma unroll
            for (int r = 0; r < 16; ++r) tv[r] = acc0[r] * k1;
            float tm = tv[0];
#pragma unroll
            for (int r = 1; r < 16; ++r) tm = fmaxf(tm, tv[r]);
            float mn = fmaxf(m0, tm);
            float ad = 0.0f;
#pragma unroll
            for (int r = 0; r < 16; ++r) ad += fexp2(tv[r] - mn);
            s0 = s0 * fexp2(m0 - mn) + ad; m0 = mn;
        }
        {
            float tv[16];
#pragma unroll
            for (int r = 0; r < 16; ++r) tv[r] = acc1[r] * k1;
            float tm = tv[0];
#pragma unroll
            for (int r = 1; r < 16; ++r) tm = fmaxf(tm, tv[r]);
            float mn = fmaxf(m1, tm);
            float ad = 0.0f;
#pragma unroll
            for (int r = 0; r < 16; ++r) ad += fexp2(tv[r] - mn);
            s1 = s1 * fexp2(m1 - mn) + ad; m1 = mn;
        }
    }
    // lanes l and l+32 hold complementary j-subsets of the same row: merge
    float mo = __shfl_xor(m0, 32), so = __shfl_xor(s0, 32);
    float M0 = fmaxf(m0, mo);
    float S0 = s0 * fexp2(m0 - M0) + so * fexp2(mo - M0);
    mo = __shfl_xor(m1, 32); so = __shfl_xor(s1, 32);
    float M1 = fmaxf(m1, mo);
    float S1 = s1 * fexp2(m1 - M1) + so * fexp2(mo - M1);
    if (lane < 32) {
        size_t r0 = (size_t)task * N + (i0 + l31);
        size_t r1 = r0 + 32;
        parts[r0 * 4 + split] = make_float2(M0, S0);
        parts[r1 * 4 + split] = make_float2(M1, S1);
    }
}

// ---------------- merge j-split partials -> new potentials + panel pot columns ----------------
__global__ void merge_pots(const float2* __restrict__ parts, float* __restrict__ pots,
                           ushort* __restrict__ pan0, ushort* __restrict__ pan1,
                           ushort* __restrict__ pan2, ushort* __restrict__ pan3,
                           float eps, float logw, int do_avg) {
    int id = blockIdx.x * 256 + threadIdx.x;  // 0..4N-1; id = task*N + row
    int task = id >> 13;
    int row = id & (N - 1);
    const float2* p = parts + (size_t)id * 4;
    float2 a = p[0], b = p[1], c = p[2], d = p[3];
    float M = fmaxf(fmaxf(a.x, b.x), fmaxf(c.x, d.x));
    float S = a.y * fexp2(a.x - M) + b.y * fexp2(b.x - M) +
              c.y * fexp2(c.x - M) + d.y * fexp2(d.x - M);
    float lse = LN2 * (M + flog2(S));      // natural-log LSE of (pot_j - C_ij)/eps
    float v = -eps * (logw + lse);
    if (do_avg && task < 2) v = 0.5f * (pots[id] + v);
    pots[id] = v;
    // panel pot columns for NEXT iteration: task0->pan0(fxx), task1->pan1(gyy),
    // task2 (f) -> pan3 (task3 streams f), task3 (g) -> pan2 (task2 streams g)
    ushort* pan;
    switch (task) {
        case 0:  pan = pan0; break;
        case 1:  pan = pan1; break;
        case 2:  pan = pan3; break;
        default: pan = pan2; break;
    }
    float pt = v - 1.0f;
    ushort hi = bf16r(pt);
    float lo = pt - bf16f(hi);
    pan[(size_t)row * KP + 256] = hi;
    pan[(size_t)row * KP + 257] = bf16r(lo);
}

// ---------------- final scalar reduce ----------------
__global__ void final_reduce(const float* __restrict__ pots, float* __restrict__ out) {
    int t = threadIdx.x;
    float s = 0.0f;
    for (int i = t; i < N; i += 256)
        s += (pots[2 * N + i] - pots[i]) + (pots[3 * N + i] - pots[N + i]);
#pragma unroll
    for (int m = 1; m < 64; m <<= 1) s += __shfl_xor(s, m);
    __shared__ float sm[4];
    if ((t & 63) == 0) sm[t >> 6] = s;
    __syncthreads();
    if (t == 0) out[0] = (sm[0] + sm[1] + sm[2] + sm[3]) * (1.0f / (float)N);
}

extern "C" void kernel_launch(void* const* d_in, const int* in_sizes, int n_in,
                              void* d_out, int out_size, void* d_ws, size_t ws_size,
                              hipStream_t stream) {
    const float* x1 = (const float*)d_in[0];
    const float* x2 = (const float*)d_in[1];
    const float* w  = (const float*)d_in[2];
    float* out = (float*)d_out;

    ushort* an_i = (ushort*)d_ws;                       // N*D bf16
    ushort* bn_i = an_i + (size_t)N * D;                // N*D
    ushort* pan0 = bn_i + (size_t)N * D;                // N*KP each
    ushort* pan1 = pan0 + (size_t)N * KP;
    ushort* pan2 = pan1 + (size_t)N * KP;
    ushort* pan3 = pan2 + (size_t)N * KP;
    float*  wc   = (float*)(pan3 + (size_t)N * KP);     // 256
    float*  pots = wc + 256;                            // 4N  (fxx,gyy,f,g)
    float2* parts = (float2*)(pots + 4 * N);            // 4N * 4 splits

    hipMemsetAsync(pots, 0, 4 * N * sizeof(float), stream);
    prep_wc<<<1, 256, 0, stream>>>(w, wc);
    prep_normalize<<<2 * N, 256, 0, stream>>>(x1, x2, wc, an_i, bn_i, pan0, pan1, pan2, pan3);

    const float eps_list[10] = {4.0f, 1.0f, 0.25f, 0.0625f, 0.015625f,
                                0.00390625f, 0.0025f, 0.0025f, 0.0025f, 0.0025f};
    const float logw = -logf((float)N);
    const float LOG2E = 1.4426950408889634f;
    for (int it = 0; it < 10; ++it) {
        softmin_mfma<<<512, 256, 0, stream>>>(an_i, bn_i, pan0, pan1, pan2, pan3,
                                              parts, LOG2E / eps_list[it]);
        merge_pots<<<4 * N / 256, 256, 0, stream>>>(parts, pots, pan0, pan1, pan2, pan3,
                                                    eps_list[it], logw, 1);
    }
    // final extrapolation at eps_final, no averaging
    softmin_mfma<<<512, 256, 0, stream>>>(an_i, bn_i, pan0, pan1, pan2, pan3,
                                          parts, LOG2E / 0.0025f);
    merge_pots<<<4 * N / 256, 256, 0, stream>>>(parts, pots, pan0, pan1, pan2, pan3,
                                                0.0025f, logw, 0);
    final_reduce<<<1, 256, 0, stream>>>(pots, out);
}